// Round 1
// baseline (1155.539 us; speedup 1.0000x reference)
//
#include <hip/hip_runtime.h>

#define CC   256
#define DHWC 65536          // D*H*W
#define NBC  2              // batch

// ---------------------------------------------------------------------------
// conv1x1: out[b,o,s] = relu?( sum_c w[o,c]*x[b,c,s] + bias[o] )
// GEMM [Cout x Cin] * [Cin x S].  Tile: 128(o) x 128(s), BK=16, 256 threads,
// 8x8 per-thread register tile (split 4+4 at distance 64 to keep LDS 2-way).
// ---------------------------------------------------------------------------
__global__ __launch_bounds__(256) void conv1x1_kernel(
    const float* __restrict__ x, const float* __restrict__ w,
    const float* __restrict__ bias, float* __restrict__ out, const int do_relu)
{
    __shared__ float ws_t[16][128];   // [k][o]
    __shared__ float xs[16][128];     // [k][s]

    const int tid = threadIdx.x;
    const int sT  = blockIdx.x * 128;
    const int oT  = blockIdx.y * 128;
    const size_t boff = (size_t)blockIdx.z * ((size_t)CC * DHWC);
    const float* xb = x + boff;
    float* ob = out + boff;

    const int ty = tid >> 4;    // 0..15
    const int tx = tid & 15;    // 0..15

    float acc[8][8];
    #pragma unroll
    for (int i = 0; i < 8; ++i)
        #pragma unroll
        for (int j = 0; j < 8; ++j) acc[i][j] = 0.f;

    for (int kT = 0; kT < CC; kT += 16) {
        __syncthreads();
        // stage W strip: 128 o x 16 k, transposed into [k][o]
        {
            const int o  = tid >> 1;
            const int k0 = (tid & 1) * 8;
            const float* wp = w + (size_t)(oT + o) * CC + kT + k0;
            const float4 wa = *(const float4*)wp;
            const float4 wb = *(const float4*)(wp + 4);
            ws_t[k0 + 0][o] = wa.x; ws_t[k0 + 1][o] = wa.y;
            ws_t[k0 + 2][o] = wa.z; ws_t[k0 + 3][o] = wa.w;
            ws_t[k0 + 4][o] = wb.x; ws_t[k0 + 5][o] = wb.y;
            ws_t[k0 + 6][o] = wb.z; ws_t[k0 + 7][o] = wb.w;
        }
        // stage X strip: 16 k x 128 s
        #pragma unroll
        for (int ch = 0; ch < 2; ++ch) {
            const int idx = tid + 256 * ch;
            const int kk  = idx >> 5;
            const int c4  = idx & 31;
            const float4 xv = *(const float4*)(xb + (size_t)(kT + kk) * DHWC + sT + 4 * c4);
            *(float4*)&xs[kk][4 * c4] = xv;
        }
        __syncthreads();

        #pragma unroll
        for (int k = 0; k < 16; ++k) {
            const float4 aL = *(const float4*)&ws_t[k][4 * ty];
            const float4 aH = *(const float4*)&ws_t[k][64 + 4 * ty];
            const float4 bL = *(const float4*)&xs[k][4 * tx];
            const float4 bH = *(const float4*)&xs[k][64 + 4 * tx];
            const float av[8] = {aL.x, aL.y, aL.z, aL.w, aH.x, aH.y, aH.z, aH.w};
            const float bv[8] = {bL.x, bL.y, bL.z, bL.w, bH.x, bH.y, bH.z, bH.w};
            #pragma unroll
            for (int i = 0; i < 8; ++i)
                #pragma unroll
                for (int j = 0; j < 8; ++j)
                    acc[i][j] = fmaf(av[i], bv[j], acc[i][j]);
        }
    }

    #pragma unroll
    for (int i = 0; i < 8; ++i) {
        const int o = oT + ((i < 4) ? (4 * ty + i) : (64 + 4 * ty + (i - 4)));
        const float bvs = bias[o];
        float* op = ob + (size_t)o * DHWC + sT;
        float4 lo = make_float4(acc[i][0] + bvs, acc[i][1] + bvs,
                                acc[i][2] + bvs, acc[i][3] + bvs);
        float4 hi = make_float4(acc[i][4] + bvs, acc[i][5] + bvs,
                                acc[i][6] + bvs, acc[i][7] + bvs);
        if (do_relu) {
            lo.x = fmaxf(lo.x, 0.f); lo.y = fmaxf(lo.y, 0.f);
            lo.z = fmaxf(lo.z, 0.f); lo.w = fmaxf(lo.w, 0.f);
            hi.x = fmaxf(hi.x, 0.f); hi.y = fmaxf(hi.y, 0.f);
            hi.z = fmaxf(hi.z, 0.f); hi.w = fmaxf(hi.w, 0.f);
        }
        *(float4*)(op + 4 * tx)      = lo;
        *(float4*)(op + 64 + 4 * tx) = hi;
    }
}

// ---------------------------------------------------------------------------
// attention: per (b,c,d) slab of [H=64][W=64]:
//   scores = softmax_x( q @ k^T ), wv = scores @ v.
// One block (256 thr) per slab. wv may alias q (slab fully staged to LDS
// before any write).  ss reuses qs's LDS (q dead after QK + barrier).
// ---------------------------------------------------------------------------
__global__ __launch_bounds__(256) void attn_kernel(
    const float* q, const float* kg,
    const float* __restrict__ v, float* wv)
{
    __shared__ float qs[64][68];
    __shared__ float ks[64][68];
    __shared__ float vs[64][68];
    float (*ss)[68] = qs;            // scores reuse q's LDS

    const int tid = threadIdx.x;
    const size_t base = (size_t)blockIdx.x * 4096;   // H*W

    #pragma unroll
    for (int ch = 0; ch < 4; ++ch) {
        const int idx = tid + 256 * ch;
        const int r  = idx >> 4;
        const int c4 = (idx & 15) * 4;
        *(float4*)&qs[r][c4] = *(const float4*)(q  + base + r * 64 + c4);
        *(float4*)&ks[r][c4] = *(const float4*)(kg + base + r * 64 + c4);
        *(float4*)&vs[r][c4] = *(const float4*)(v  + base + r * 64 + c4);
    }
    __syncthreads();

    const int h0 = (tid >> 4) * 4;   // 4 consecutive rows
    const int m  = tid & 15;         // x = m + 16*j (strided)

    float sc[4][4];
    #pragma unroll
    for (int i = 0; i < 4; ++i)
        #pragma unroll
        for (int j = 0; j < 4; ++j) sc[i][j] = 0.f;

    #pragma unroll
    for (int w4 = 0; w4 < 16; ++w4) {
        float4 q4[4], k4[4];
        #pragma unroll
        for (int i = 0; i < 4; ++i) q4[i] = *(const float4*)&qs[h0 + i][4 * w4];
        #pragma unroll
        for (int j = 0; j < 4; ++j) k4[j] = *(const float4*)&ks[m + 16 * j][4 * w4];
        #pragma unroll
        for (int i = 0; i < 4; ++i)
            #pragma unroll
            for (int j = 0; j < 4; ++j)
                sc[i][j] += q4[i].x * k4[j].x + q4[i].y * k4[j].y +
                            q4[i].z * k4[j].z + q4[i].w * k4[j].w;
    }

    // softmax over x: 4 regs per row per lane, 16 lanes per row
    float p[4][4], inv[4];
    #pragma unroll
    for (int i = 0; i < 4; ++i) {
        float rm = fmaxf(fmaxf(sc[i][0], sc[i][1]), fmaxf(sc[i][2], sc[i][3]));
        rm = fmaxf(rm, __shfl_xor(rm, 1, 16));
        rm = fmaxf(rm, __shfl_xor(rm, 2, 16));
        rm = fmaxf(rm, __shfl_xor(rm, 4, 16));
        rm = fmaxf(rm, __shfl_xor(rm, 8, 16));
        float rs = 0.f;
        #pragma unroll
        for (int j = 0; j < 4; ++j) { p[i][j] = __expf(sc[i][j] - rm); rs += p[i][j]; }
        rs += __shfl_xor(rs, 1, 16);
        rs += __shfl_xor(rs, 2, 16);
        rs += __shfl_xor(rs, 4, 16);
        rs += __shfl_xor(rs, 8, 16);
        inv[i] = 1.f / rs;
    }
    __syncthreads();                 // all QK reads of qs done -> safe to overwrite
    #pragma unroll
    for (int i = 0; i < 4; ++i)
        #pragma unroll
        for (int j = 0; j < 4; ++j)
            ss[h0 + i][m + 16 * j] = p[i][j] * inv[i];
    __syncthreads();

    // PV: rows h0..h0+3, cols w = 4m..4m+3
    float4 o4[4];
    #pragma unroll
    for (int i = 0; i < 4; ++i) o4[i] = make_float4(0.f, 0.f, 0.f, 0.f);

    #pragma unroll
    for (int x4 = 0; x4 < 16; ++x4) {
        float4 s4[4];
        #pragma unroll
        for (int i = 0; i < 4; ++i) s4[i] = *(const float4*)&ss[h0 + i][4 * x4];
        #pragma unroll
        for (int xx = 0; xx < 4; ++xx) {
            const float4 v4 = *(const float4*)&vs[4 * x4 + xx][4 * m];
            #pragma unroll
            for (int i = 0; i < 4; ++i) {
                const float f = ((const float*)&s4[i])[xx];
                o4[i].x = fmaf(f, v4.x, o4[i].x);
                o4[i].y = fmaf(f, v4.y, o4[i].y);
                o4[i].z = fmaf(f, v4.z, o4[i].z);
                o4[i].w = fmaf(f, v4.w, o4[i].w);
            }
        }
    }
    #pragma unroll
    for (int i = 0; i < 4; ++i)
        *(float4*)(wv + base + (h0 + i) * 64 + 4 * m) = o4[i];
}

// ---------------------------------------------------------------------------
// Pipeline: q=conv(eeg), k=conv(img), v=conv(img) -> attn -> a=relu(conv(wv))
//           -> out=relu(conv(a)).
// Buffers: qbuf,kbuf in ws (2 x 134MB); v in d_out; wv overwrites qbuf
// (in-place, block-local slab); a overwrites kbuf; final overwrites d_out.
// ---------------------------------------------------------------------------
extern "C" void kernel_launch(void* const* d_in, const int* in_sizes, int n_in,
                              void* d_out, int out_size, void* d_ws, size_t ws_size,
                              hipStream_t stream)
{
    const float* eeg    = (const float*)d_in[0];
    const float* img    = (const float*)d_in[1];
    const float* q_w    = (const float*)d_in[2];
    const float* q_b    = (const float*)d_in[3];
    const float* k_w    = (const float*)d_in[4];
    const float* k_b    = (const float*)d_in[5];
    const float* v_w    = (const float*)d_in[6];
    const float* v_b    = (const float*)d_in[7];
    const float* attn_w = (const float*)d_in[8];
    const float* attn_b = (const float*)d_in[9];
    const float* out_w  = (const float*)d_in[10];
    const float* out_b  = (const float*)d_in[11];

    float* outp = (float*)d_out;
    const size_t N = (size_t)NBC * CC * DHWC;     // 33,554,432 elements
    float* qbuf = (float*)d_ws;
    float* kbuf = qbuf + N;

    const dim3 cgrid(DHWC / 128, CC / 128, NBC);
    const dim3 cblk(256);

    hipLaunchKernelGGL(conv1x1_kernel, cgrid, cblk, 0, stream, eeg, q_w, q_b, qbuf, 0);
    hipLaunchKernelGGL(conv1x1_kernel, cgrid, cblk, 0, stream, img, k_w, k_b, kbuf, 0);
    hipLaunchKernelGGL(conv1x1_kernel, cgrid, cblk, 0, stream, img, v_w, v_b, outp, 0);
    hipLaunchKernelGGL(attn_kernel, dim3(NBC * CC * 16), cblk, 0, stream,
                       qbuf, kbuf, outp, qbuf);
    hipLaunchKernelGGL(conv1x1_kernel, cgrid, cblk, 0, stream, qbuf, attn_w, attn_b, kbuf, 1);
    hipLaunchKernelGGL(conv1x1_kernel, cgrid, cblk, 0, stream, kbuf, out_w, out_b, outp, 1);
}

// Round 2
// 558.689 us; speedup vs baseline: 2.0683x; 2.0683x over previous
//
#include <hip/hip_runtime.h>

#define CC   256
#define DHWC 65536          // D*H*W
#define NBC  2              // batch

typedef __attribute__((ext_vector_type(8))) short bf16x8;
typedef __attribute__((ext_vector_type(4))) float f32x4;

// ---- bf16 split helpers (branchless, bit-level, RTN-even) --------------------
__device__ __forceinline__ short f2bf(float x) {
    unsigned u = __builtin_bit_cast(unsigned, x);
    unsigned r = (u + 0x7fffu + ((u >> 16) & 1u)) >> 16;
    return (short)r;
}
__device__ __forceinline__ float bf2f(short h) {
    unsigned u = ((unsigned)(unsigned short)h) << 16;
    return __builtin_bit_cast(float, u);
}

// swizzled byte offset into a [64 s][64 k] bf16 LDS tile (row stride 128 B).
// XOR of bits 4-6 with (s&7) spreads the 128B-stride rows across 8 16B slots.
__device__ __forceinline__ int swz(int s, int k) {
    return (s * 128 + k * 2) ^ ((s & 7) << 4);
}

// ---------------------------------------------------------------------------
// prep: split 5 weight matrices [256][256] fp32 into hi/lo bf16 planes stored
// fragment-major for mfma_f32_16x16x32_bf16 A-operand:
//   frag (fo = o/16, t = k/32): lane l holds W[fo*16 + (l&15)][t*32 + (l>>4)*8 + r]
// layout: matrix m at wsp + m*2*65536 shorts (hi plane, then lo plane);
//   frag idx = (fo*8 + t)*64 + lane, 8 shorts each.
// ---------------------------------------------------------------------------
__global__ void prep_w_kernel(const float* __restrict__ q_w, const float* __restrict__ k_w,
                              const float* __restrict__ v_w, const float* __restrict__ attn_w,
                              const float* __restrict__ out_w, short* __restrict__ wsp)
{
    const int l  = threadIdx.x;          // 64
    const int fo = blockIdx.x;           // 16
    const int t  = blockIdx.y;           // 8
    const int m  = blockIdx.z;           // 5
    const float* w = (m == 0) ? q_w : (m == 1) ? k_w : (m == 2) ? v_w
                   : (m == 3) ? attn_w : out_w;
    short* whi = wsp + (size_t)m * 2 * 65536;
    short* wlo = whi + 65536;

    const int o = fo * 16 + (l & 15);
    const int k = t * 32 + (l >> 4) * 8;

    bf16x8 hv, lv;
    #pragma unroll
    for (int r = 0; r < 8; ++r) {
        const float x = w[o * 256 + k + r];
        const short h = f2bf(x);
        hv[r] = h;
        lv[r] = f2bf(x - bf2f(h));
    }
    const int idx = (fo * 8 + t) * 64 + l;
    *(bf16x8*)(whi + idx * 8) = hv;
    *(bf16x8*)(wlo + idx * 8) = lv;
}

// ---------------------------------------------------------------------------
// conv1x1 via split-bf16 MFMA.
// out[o,s] = relu?( sum_c W[o,c] x[c,s] + b[o] ),  M=256(o), K=256(c), N=64/block(s)
// Block: 512 thr = 8 waves; wave w owns o in [w*32, w*32+32) (fo = 2w, 2w+1).
// A (weights) hi/lo: persistent registers, loaded frag-major (coalesced).
// B (x) staged per K-step (BK=64): fp32 global -> split bf16 -> LDS [s][k] swizzled.
// 3 MFMAs per product pair: Ahi*Bhi + Ahi*Blo + Alo*Bhi.
// ---------------------------------------------------------------------------
__global__ __launch_bounds__(512, 2) void conv_mfma_kernel(
    const float* __restrict__ x, const short* __restrict__ whi,
    const short* __restrict__ wlo, const float* __restrict__ bias,
    float* __restrict__ out, const int do_relu)
{
    __shared__ bf16x8 xhi[2][512];   // [buf][64 s][64 k] bf16, 8 KB each
    __shared__ bf16x8 xlo[2][512];

    const int tid  = threadIdx.x;
    const int lane = tid & 63;
    const int wave = tid >> 6;            // 0..7
    const size_t boff = (size_t)blockIdx.y * ((size_t)CC * DHWC);
    const int sT = blockIdx.x * 64;
    const float* xb = x + boff + sT;

    // ---- persistent A fragments (whole K=256, hi+lo) : 128 VGPRs ----
    bf16x8 ahi[2][8], alo[2][8];
    {
        const bf16x8* whf = (const bf16x8*)whi;
        const bf16x8* wlf = (const bf16x8*)wlo;
        #pragma unroll
        for (int f = 0; f < 2; ++f) {
            const int fo = wave * 2 + f;
            #pragma unroll
            for (int t = 0; t < 8; ++t) {
                ahi[f][t] = whf[(fo * 8 + t) * 64 + lane];
                alo[f][t] = wlf[(fo * 8 + t) * 64 + lane];
            }
        }
    }

    f32x4 acc[2][4];
    #pragma unroll
    for (int f = 0; f < 2; ++f)
        #pragma unroll
        for (int j = 0; j < 4; ++j)
            acc[f][j] = (f32x4){0.f, 0.f, 0.f, 0.f};

    // staging role of this thread: one s column, 8 consecutive k rows
    const int s_l = tid & 63;
    const int k8  = tid >> 6;     // 0..7 -> k = k8*8 + r

    float xr[8];
    // prologue: load + stage k-step 0
    #pragma unroll
    for (int r = 0; r < 8; ++r)
        xr[r] = xb[(size_t)(k8 * 8 + r) * DHWC + s_l];
    {
        bf16x8 hv, lv;
        #pragma unroll
        for (int r = 0; r < 8; ++r) {
            const short h = f2bf(xr[r]);
            hv[r] = h;
            lv[r] = f2bf(xr[r] - bf2f(h));
        }
        *(bf16x8*)((char*)xhi[0] + swz(s_l, k8 * 8)) = hv;
        *(bf16x8*)((char*)xlo[0] + swz(s_l, k8 * 8)) = lv;
    }

    #pragma unroll
    for (int t = 0; t < 4; ++t) {         // K-steps of 64
        if (t < 3) {                      // issue next-step global loads early
            #pragma unroll
            for (int r = 0; r < 8; ++r)
                xr[r] = xb[(size_t)((t + 1) * 64 + k8 * 8 + r) * DHWC + s_l];
        }
        __syncthreads();                  // buf[t&1] staged & prior reads done

        const char* bhib = (const char*)xhi[t & 1];
        const char* blob = (const char*)xlo[t & 1];
        #pragma unroll
        for (int kk = 0; kk < 2; ++kk) {  // two K=32 halves of this step
            bf16x8 bh[4], bl[4];
            #pragma unroll
            for (int j = 0; j < 4; ++j) {
                const int s = j * 16 + (lane & 15);
                const int k = kk * 32 + (lane >> 4) * 8;
                bh[j] = *(const bf16x8*)(bhib + swz(s, k));
                bl[j] = *(const bf16x8*)(blob + swz(s, k));
            }
            #pragma unroll
            for (int f = 0; f < 2; ++f)
                #pragma unroll
                for (int j = 0; j < 4; ++j) {
                    f32x4 c = acc[f][j];
                    c = __builtin_amdgcn_mfma_f32_16x16x32_bf16(ahi[f][2 * t + kk], bh[j], c, 0, 0, 0);
                    c = __builtin_amdgcn_mfma_f32_16x16x32_bf16(ahi[f][2 * t + kk], bl[j], c, 0, 0, 0);
                    c = __builtin_amdgcn_mfma_f32_16x16x32_bf16(alo[f][2 * t + kk], bh[j], c, 0, 0, 0);
                    acc[f][j] = c;
                }
        }

        if (t < 3) {                      // convert + stage into other buffer
            bf16x8 hv, lv;
            #pragma unroll
            for (int r = 0; r < 8; ++r) {
                const short h = f2bf(xr[r]);
                hv[r] = h;
                lv[r] = f2bf(xr[r] - bf2f(h));
            }
            *(bf16x8*)((char*)xhi[(t + 1) & 1] + swz(s_l, k8 * 8)) = hv;
            *(bf16x8*)((char*)xlo[(t + 1) & 1] + swz(s_l, k8 * 8)) = lv;
        }
    }

    // ---- epilogue: D[m][n] -> o = fo*16 + (lane>>4)*4 + r, s = j*16 + (lane&15)
    float* ob = out + boff + sT;
    const int n_l = lane & 15;
    const int m4  = (lane >> 4) * 4;
    #pragma unroll
    for (int f = 0; f < 2; ++f) {
        #pragma unroll
        for (int r = 0; r < 4; ++r) {
            const int o = wave * 32 + f * 16 + m4 + r;
            const float bv = bias[o];
            #pragma unroll
            for (int j = 0; j < 4; ++j) {
                float val = acc[f][j][r] + bv;
                if (do_relu) val = fmaxf(val, 0.f);
                ob[(size_t)o * DHWC + j * 16 + n_l] = val;
            }
        }
    }
}

// ---------------------------------------------------------------------------
// attention: per (b,c,d) slab of [H=64][W=64] (unchanged from round 1)
// ---------------------------------------------------------------------------
__global__ __launch_bounds__(256) void attn_kernel(
    const float* q, const float* kg,
    const float* __restrict__ v, float* wv)
{
    __shared__ float qs[64][68];
    __shared__ float ks[64][68];
    __shared__ float vs[64][68];
    float (*ss)[68] = qs;            // scores reuse q's LDS

    const int tid = threadIdx.x;
    const size_t base = (size_t)blockIdx.x * 4096;   // H*W

    #pragma unroll
    for (int ch = 0; ch < 4; ++ch) {
        const int idx = tid + 256 * ch;
        const int r  = idx >> 4;
        const int c4 = (idx & 15) * 4;
        *(float4*)&qs[r][c4] = *(const float4*)(q  + base + r * 64 + c4);
        *(float4*)&ks[r][c4] = *(const float4*)(kg + base + r * 64 + c4);
        *(float4*)&vs[r][c4] = *(const float4*)(v  + base + r * 64 + c4);
    }
    __syncthreads();

    const int h0 = (tid >> 4) * 4;   // 4 consecutive rows
    const int m  = tid & 15;         // x = m + 16*j (strided)

    float sc[4][4];
    #pragma unroll
    for (int i = 0; i < 4; ++i)
        #pragma unroll
        for (int j = 0; j < 4; ++j) sc[i][j] = 0.f;

    #pragma unroll
    for (int w4 = 0; w4 < 16; ++w4) {
        float4 q4[4], k4[4];
        #pragma unroll
        for (int i = 0; i < 4; ++i) q4[i] = *(const float4*)&qs[h0 + i][4 * w4];
        #pragma unroll
        for (int j = 0; j < 4; ++j) k4[j] = *(const float4*)&ks[m + 16 * j][4 * w4];
        #pragma unroll
        for (int i = 0; i < 4; ++i)
            #pragma unroll
            for (int j = 0; j < 4; ++j)
                sc[i][j] += q4[i].x * k4[j].x + q4[i].y * k4[j].y +
                            q4[i].z * k4[j].z + q4[i].w * k4[j].w;
    }

    float p[4][4], inv[4];
    #pragma unroll
    for (int i = 0; i < 4; ++i) {
        float rm = fmaxf(fmaxf(sc[i][0], sc[i][1]), fmaxf(sc[i][2], sc[i][3]));
        rm = fmaxf(rm, __shfl_xor(rm, 1, 16));
        rm = fmaxf(rm, __shfl_xor(rm, 2, 16));
        rm = fmaxf(rm, __shfl_xor(rm, 4, 16));
        rm = fmaxf(rm, __shfl_xor(rm, 8, 16));
        float rs = 0.f;
        #pragma unroll
        for (int j = 0; j < 4; ++j) { p[i][j] = __expf(sc[i][j] - rm); rs += p[i][j]; }
        rs += __shfl_xor(rs, 1, 16);
        rs += __shfl_xor(rs, 2, 16);
        rs += __shfl_xor(rs, 4, 16);
        rs += __shfl_xor(rs, 8, 16);
        inv[i] = 1.f / rs;
    }
    __syncthreads();
    #pragma unroll
    for (int i = 0; i < 4; ++i)
        #pragma unroll
        for (int j = 0; j < 4; ++j)
            ss[h0 + i][m + 16 * j] = p[i][j] * inv[i];
    __syncthreads();

    float4 o4[4];
    #pragma unroll
    for (int i = 0; i < 4; ++i) o4[i] = make_float4(0.f, 0.f, 0.f, 0.f);

    #pragma unroll
    for (int x4 = 0; x4 < 16; ++x4) {
        float4 s4[4];
        #pragma unroll
        for (int i = 0; i < 4; ++i) s4[i] = *(const float4*)&ss[h0 + i][4 * x4];
        #pragma unroll
        for (int xx = 0; xx < 4; ++xx) {
            const float4 v4 = *(const float4*)&vs[4 * x4 + xx][4 * m];
            #pragma unroll
            for (int i = 0; i < 4; ++i) {
                const float f = ((const float*)&s4[i])[xx];
                o4[i].x = fmaf(f, v4.x, o4[i].x);
                o4[i].y = fmaf(f, v4.y, o4[i].y);
                o4[i].z = fmaf(f, v4.z, o4[i].z);
                o4[i].w = fmaf(f, v4.w, o4[i].w);
            }
        }
    }
    #pragma unroll
    for (int i = 0; i < 4; ++i)
        *(float4*)(wv + base + (h0 + i) * 64 + 4 * m) = o4[i];
}

// ---------------------------------------------------------------------------
// Pipeline: prep W -> q=conv(eeg), k=conv(img), v=conv(img) -> attn ->
//           a=relu(conv(wv)) -> out=relu(conv(a)).
// ws: qbuf (N f32) | kbuf (N f32) | wsplit (5 x 2 x 65536 bf16 = 1.25 MB)
// ---------------------------------------------------------------------------
extern "C" void kernel_launch(void* const* d_in, const int* in_sizes, int n_in,
                              void* d_out, int out_size, void* d_ws, size_t ws_size,
                              hipStream_t stream)
{
    const float* eeg    = (const float*)d_in[0];
    const float* img    = (const float*)d_in[1];
    const float* q_w    = (const float*)d_in[2];
    const float* q_b    = (const float*)d_in[3];
    const float* k_w    = (const float*)d_in[4];
    const float* k_b    = (const float*)d_in[5];
    const float* v_w    = (const float*)d_in[6];
    const float* v_b    = (const float*)d_in[7];
    const float* attn_w = (const float*)d_in[8];
    const float* attn_b = (const float*)d_in[9];
    const float* out_w  = (const float*)d_in[10];
    const float* out_b  = (const float*)d_in[11];

    float* outp = (float*)d_out;
    const size_t N = (size_t)NBC * CC * DHWC;     // 33,554,432 elements
    float* qbuf = (float*)d_ws;
    float* kbuf = qbuf + N;
    short* wsp  = (short*)(kbuf + N);             // 5 * 2 * 65536 shorts

    hipLaunchKernelGGL(prep_w_kernel, dim3(16, 8, 5), dim3(64), 0, stream,
                       q_w, k_w, v_w, attn_w, out_w, wsp);

    const dim3 cgrid(DHWC / 64, NBC);
    const dim3 cblk(512);
    #define WMAT(m) (wsp + (size_t)(m) * 2 * 65536), (wsp + (size_t)(m) * 2 * 65536 + 65536)

    hipLaunchKernelGGL(conv_mfma_kernel, cgrid, cblk, 0, stream, eeg,  WMAT(0), q_b,    qbuf, 0);
    hipLaunchKernelGGL(conv_mfma_kernel, cgrid, cblk, 0, stream, img,  WMAT(1), k_b,    kbuf, 0);
    hipLaunchKernelGGL(conv_mfma_kernel, cgrid, cblk, 0, stream, img,  WMAT(2), v_b,    outp, 0);
    hipLaunchKernelGGL(attn_kernel, dim3(NBC * CC * 16), dim3(256), 0, stream,
                       qbuf, kbuf, outp, qbuf);
    hipLaunchKernelGGL(conv_mfma_kernel, cgrid, cblk, 0, stream, qbuf, WMAT(3), attn_b, kbuf, 1);
    hipLaunchKernelGGL(conv_mfma_kernel, cgrid, cblk, 0, stream, kbuf, WMAT(4), out_b,  outp, 1);
    #undef WMAT
}

// Round 3
// 487.106 us; speedup vs baseline: 2.3723x; 1.1470x over previous
//
#include <hip/hip_runtime.h>

#define CC   256
#define DHWC 65536          // D*H*W
#define NBC  2              // batch

typedef __attribute__((ext_vector_type(8))) short bf16x8;
typedef __attribute__((ext_vector_type(4))) short bf16x4;
typedef __attribute__((ext_vector_type(4))) float f32x4;

// ---- bf16 split helpers (branchless, bit-level, RTN-even) --------------------
__device__ __forceinline__ short f2bf(float x) {
    unsigned u = __builtin_bit_cast(unsigned, x);
    unsigned r = (u + 0x7fffu + ((u >> 16) & 1u)) >> 16;
    return (short)r;
}
__device__ __forceinline__ float bf2f(short h) {
    unsigned u = ((unsigned)(unsigned short)h) << 16;
    return __builtin_bit_cast(float, u);
}

// swizzled byte offset into a [64 r][64 c] bf16 LDS plane (row stride 128 B).
__device__ __forceinline__ int swz(int r, int c) {
    return (r * 128 + c * 2) ^ ((r & 7) << 4);
}
// swizzled byte offset into a [64 s][256 k] bf16 LDS plane (row stride 512 B).
__device__ __forceinline__ int swz512(int s, int k) {
    return (s * 512 + k * 2) ^ ((s & 7) << 4);
}

// ---------------------------------------------------------------------------
// prep: split 5 weight matrices [256][256] fp32 into hi/lo bf16 planes stored
// fragment-major for mfma_f32_16x16x32_bf16 A-operand:
//   frag (fo = o/16, t = k/32): lane l holds W[fo*16 + (l&15)][t*32 + (l>>4)*8 + r]
// ---------------------------------------------------------------------------
__global__ void prep_w_kernel(const float* __restrict__ q_w, const float* __restrict__ k_w,
                              const float* __restrict__ v_w, const float* __restrict__ attn_w,
                              const float* __restrict__ out_w, short* __restrict__ wsp)
{
    const int l  = threadIdx.x;          // 64
    const int fo = blockIdx.x;           // 16
    const int t  = blockIdx.y;           // 8
    const int m  = blockIdx.z;           // 5
    const float* w = (m == 0) ? q_w : (m == 1) ? k_w : (m == 2) ? v_w
                   : (m == 3) ? attn_w : out_w;
    short* whi = wsp + (size_t)m * 2 * 65536;
    short* wlo = whi + 65536;

    const int o = fo * 16 + (l & 15);
    const int k = t * 32 + (l >> 4) * 8;

    bf16x8 hv, lv;
    #pragma unroll
    for (int r = 0; r < 8; ++r) {
        const float x = w[o * 256 + k + r];
        const short h = f2bf(x);
        hv[r] = h;
        lv[r] = f2bf(x - bf2f(h));
    }
    const int idx = (fo * 8 + t) * 64 + l;
    *(bf16x8*)(whi + idx * 8) = hv;
    *(bf16x8*)(wlo + idx * 8) = lv;
}

// ---------------------------------------------------------------------------
// conv1x1 via split-bf16 MFMA (unchanged from round 2).
// ---------------------------------------------------------------------------
__global__ __launch_bounds__(512, 2) void conv_mfma_kernel(
    const float* __restrict__ x, const short* __restrict__ whi,
    const short* __restrict__ wlo, const float* __restrict__ bias,
    float* __restrict__ out, const int do_relu)
{
    __shared__ bf16x8 xhi[2][512];   // [buf][64 s][64 k] bf16, 8 KB each
    __shared__ bf16x8 xlo[2][512];

    const int tid  = threadIdx.x;
    const int lane = tid & 63;
    const int wave = tid >> 6;            // 0..7
    const size_t boff = (size_t)blockIdx.y * ((size_t)CC * DHWC);
    const int sT = blockIdx.x * 64;
    const float* xb = x + boff + sT;

    bf16x8 ahi[2][8], alo[2][8];
    {
        const bf16x8* whf = (const bf16x8*)whi;
        const bf16x8* wlf = (const bf16x8*)wlo;
        #pragma unroll
        for (int f = 0; f < 2; ++f) {
            const int fo = wave * 2 + f;
            #pragma unroll
            for (int t = 0; t < 8; ++t) {
                ahi[f][t] = whf[(fo * 8 + t) * 64 + lane];
                alo[f][t] = wlf[(fo * 8 + t) * 64 + lane];
            }
        }
    }

    f32x4 acc[2][4];
    #pragma unroll
    for (int f = 0; f < 2; ++f)
        #pragma unroll
        for (int j = 0; j < 4; ++j)
            acc[f][j] = (f32x4){0.f, 0.f, 0.f, 0.f};

    const int s_l = tid & 63;
    const int k8  = tid >> 6;

    float xr[8];
    #pragma unroll
    for (int r = 0; r < 8; ++r)
        xr[r] = xb[(size_t)(k8 * 8 + r) * DHWC + s_l];
    {
        bf16x8 hv, lv;
        #pragma unroll
        for (int r = 0; r < 8; ++r) {
            const short h = f2bf(xr[r]);
            hv[r] = h;
            lv[r] = f2bf(xr[r] - bf2f(h));
        }
        *(bf16x8*)((char*)xhi[0] + swz(s_l, k8 * 8)) = hv;
        *(bf16x8*)((char*)xlo[0] + swz(s_l, k8 * 8)) = lv;
    }

    #pragma unroll
    for (int t = 0; t < 4; ++t) {
        if (t < 3) {
            #pragma unroll
            for (int r = 0; r < 8; ++r)
                xr[r] = xb[(size_t)((t + 1) * 64 + k8 * 8 + r) * DHWC + s_l];
        }
        __syncthreads();

        const char* bhib = (const char*)xhi[t & 1];
        const char* blob = (const char*)xlo[t & 1];
        #pragma unroll
        for (int kk = 0; kk < 2; ++kk) {
            bf16x8 bh[4], bl[4];
            #pragma unroll
            for (int j = 0; j < 4; ++j) {
                const int s = j * 16 + (lane & 15);
                const int k = kk * 32 + (lane >> 4) * 8;
                bh[j] = *(const bf16x8*)(bhib + swz(s, k));
                bl[j] = *(const bf16x8*)(blob + swz(s, k));
            }
            #pragma unroll
            for (int f = 0; f < 2; ++f)
                #pragma unroll
                for (int j = 0; j < 4; ++j) {
                    f32x4 c = acc[f][j];
                    c = __builtin_amdgcn_mfma_f32_16x16x32_bf16(ahi[f][2 * t + kk], bh[j], c, 0, 0, 0);
                    c = __builtin_amdgcn_mfma_f32_16x16x32_bf16(ahi[f][2 * t + kk], bl[j], c, 0, 0, 0);
                    c = __builtin_amdgcn_mfma_f32_16x16x32_bf16(alo[f][2 * t + kk], bh[j], c, 0, 0, 0);
                    acc[f][j] = c;
                }
        }

        if (t < 3) {
            bf16x8 hv, lv;
            #pragma unroll
            for (int r = 0; r < 8; ++r) {
                const short h = f2bf(xr[r]);
                hv[r] = h;
                lv[r] = f2bf(xr[r] - bf2f(h));
            }
            *(bf16x8*)((char*)xhi[(t + 1) & 1] + swz(s_l, k8 * 8)) = hv;
            *(bf16x8*)((char*)xlo[(t + 1) & 1] + swz(s_l, k8 * 8)) = lv;
        }
    }

    float* ob = out + boff + sT;
    const int n_l = lane & 15;
    const int m4  = (lane >> 4) * 4;
    #pragma unroll
    for (int f = 0; f < 2; ++f) {
        #pragma unroll
        for (int r = 0; r < 4; ++r) {
            const int o = wave * 32 + f * 16 + m4 + r;
            const float bv = bias[o];
            #pragma unroll
            for (int j = 0; j < 4; ++j) {
                float val = acc[f][j][r] + bv;
                if (do_relu) val = fmaxf(val, 0.f);
                ob[(size_t)o * DHWC + j * 16 + n_l] = val;
            }
        }
    }
}

// ---------------------------------------------------------------------------
// attention via split-bf16 MFMA. One block (256 thr = 4 waves) per (b,c,d)
// slab of [H=64][W=64]. Wave ws owns output rows [16ws, 16ws+16).
// LDS planes (each 8 KB, XOR-swizzled): qhi qlo khi klo vthi vtlo.
// P (unnormalized softmax numerator) reuses q planes; normalize at epilogue.
// ---------------------------------------------------------------------------
__global__ __launch_bounds__(256) void attn_mfma_kernel(
    const float* __restrict__ q, const float* __restrict__ kg,
    const float* __restrict__ v, float* __restrict__ wv)
{
    __shared__ char lds[49152];
    const int QHI = 0, QLO = 8192, KHI = 16384, KLO = 24576, VTHI = 32768, VTLO = 40960;

    const int tid  = threadIdx.x;
    const int lane = tid & 63;
    const int wsx  = tid >> 6;           // wave 0..3
    const size_t base = (size_t)blockIdx.x * 4096;

    // ---- stage q, k row-major split-bf16 ----
    {
        const int r  = tid >> 2;         // 0..63
        const int cb = (tid & 3) * 16;
        #pragma unroll
        for (int half = 0; half < 2; ++half) {
            const int c = cb + half * 8;
            const float4 qa = *(const float4*)(q  + base + r * 64 + c);
            const float4 qb = *(const float4*)(q  + base + r * 64 + c + 4);
            const float4 ka = *(const float4*)(kg + base + r * 64 + c);
            const float4 kb = *(const float4*)(kg + base + r * 64 + c + 4);
            bf16x8 qh, ql, kh, kl;
            #pragma unroll
            for (int e = 0; e < 4; ++e) {
                float xq = ((const float*)&qa)[e];
                short h = f2bf(xq); qh[e] = h; ql[e] = f2bf(xq - bf2f(h));
                xq = ((const float*)&qb)[e];
                h = f2bf(xq); qh[e + 4] = h; ql[e + 4] = f2bf(xq - bf2f(h));
                float xk = ((const float*)&ka)[e];
                h = f2bf(xk); kh[e] = h; kl[e] = f2bf(xk - bf2f(h));
                xk = ((const float*)&kb)[e];
                h = f2bf(xk); kh[e + 4] = h; kl[e + 4] = f2bf(xk - bf2f(h));
            }
            const int off = swz(r, c);
            *(bf16x8*)(lds + QHI + off) = qh;
            *(bf16x8*)(lds + QLO + off) = ql;
            *(bf16x8*)(lds + KHI + off) = kh;
            *(bf16x8*)(lds + KLO + off) = kl;
        }
        // ---- stage V transposed: vt[w][x] = V[x][w] ----
        const int x0 = (tid >> 4) * 4;   // 0..60
        const int w0 = (tid & 15) * 4;   // 0..60
        float4 vr[4];
        #pragma unroll
        for (int i = 0; i < 4; ++i)
            vr[i] = *(const float4*)(v + base + (size_t)(x0 + i) * 64 + w0);
        #pragma unroll
        for (int j = 0; j < 4; ++j) {
            bf16x4 h4, l4;
            #pragma unroll
            for (int i = 0; i < 4; ++i) {
                const float xv = ((const float*)&vr[i])[j];
                const short h = f2bf(xv);
                h4[i] = h;
                l4[i] = f2bf(xv - bf2f(h));
            }
            const int off = swz(w0 + j, x0);
            *(bf16x4*)(lds + VTHI + off) = h4;
            *(bf16x4*)(lds + VTLO + off) = l4;
        }
    }
    __syncthreads();

    // ---- QK^T: S[h][x] for h in own strip ----
    f32x4 acc[4];
    #pragma unroll
    for (int j = 0; j < 4; ++j) acc[j] = (f32x4){0.f, 0.f, 0.f, 0.f};

    const int arow = wsx * 16 + (lane & 15);
    #pragma unroll
    for (int kk = 0; kk < 2; ++kk) {
        const int kcol = kk * 32 + (lane >> 4) * 8;
        const bf16x8 aqh = *(const bf16x8*)(lds + QHI + swz(arow, kcol));
        const bf16x8 aql = *(const bf16x8*)(lds + QLO + swz(arow, kcol));
        #pragma unroll
        for (int j = 0; j < 4; ++j) {
            const int brow = j * 16 + (lane & 15);
            const bf16x8 bkh = *(const bf16x8*)(lds + KHI + swz(brow, kcol));
            const bf16x8 bkl = *(const bf16x8*)(lds + KLO + swz(brow, kcol));
            f32x4 c = acc[j];
            c = __builtin_amdgcn_mfma_f32_16x16x32_bf16(aqh, bkh, c, 0, 0, 0);
            c = __builtin_amdgcn_mfma_f32_16x16x32_bf16(aqh, bkl, c, 0, 0, 0);
            c = __builtin_amdgcn_mfma_f32_16x16x32_bf16(aql, bkh, c, 0, 0, 0);
            acc[j] = c;
        }
    }

    // ---- softmax over x (rows of S). Row r of lane: h = 16ws + (l>>4)*4 + r.
    float p[4][4], invs[4];
    #pragma unroll
    for (int r = 0; r < 4; ++r) {
        float m = fmaxf(fmaxf(acc[0][r], acc[1][r]), fmaxf(acc[2][r], acc[3][r]));
        m = fmaxf(m, __shfl_xor(m, 1));
        m = fmaxf(m, __shfl_xor(m, 2));
        m = fmaxf(m, __shfl_xor(m, 4));
        m = fmaxf(m, __shfl_xor(m, 8));
        float s = 0.f;
        #pragma unroll
        for (int j = 0; j < 4; ++j) { p[j][r] = __expf(acc[j][r] - m); s += p[j][r]; }
        s += __shfl_xor(s, 1);
        s += __shfl_xor(s, 2);
        s += __shfl_xor(s, 4);
        s += __shfl_xor(s, 8);
        invs[r] = 1.f / s;
    }

    __syncthreads();   // all QK reads of q planes done -> safe to overwrite with P

    // ---- write unnormalized P (split) into q planes, own strip rows ----
    #pragma unroll
    for (int r = 0; r < 4; ++r) {
        const int row = wsx * 16 + (lane >> 4) * 4 + r;
        #pragma unroll
        for (int j = 0; j < 4; ++j) {
            const int col = j * 16 + (lane & 15);
            const float pv = p[j][r];
            const short h = f2bf(pv);
            const int off = swz(row, col);
            *(short*)(lds + QHI + off) = h;
            *(short*)(lds + QLO + off) = f2bf(pv - bf2f(h));
        }
    }
    __syncthreads();

    // ---- PV: wv[h][w] = sum_x P[h][x] V[x][w] ----
    f32x4 o_[4];
    #pragma unroll
    for (int j = 0; j < 4; ++j) o_[j] = (f32x4){0.f, 0.f, 0.f, 0.f};

    #pragma unroll
    for (int kk = 0; kk < 2; ++kk) {
        const int kcol = kk * 32 + (lane >> 4) * 8;
        const bf16x8 aph = *(const bf16x8*)(lds + QHI + swz(arow, kcol));
        const bf16x8 apl = *(const bf16x8*)(lds + QLO + swz(arow, kcol));
        #pragma unroll
        for (int j = 0; j < 4; ++j) {
            const int brow = j * 16 + (lane & 15);
            const bf16x8 bvh = *(const bf16x8*)(lds + VTHI + swz(brow, kcol));
            const bf16x8 bvl = *(const bf16x8*)(lds + VTLO + swz(brow, kcol));
            f32x4 c = o_[j];
            c = __builtin_amdgcn_mfma_f32_16x16x32_bf16(aph, bvh, c, 0, 0, 0);
            c = __builtin_amdgcn_mfma_f32_16x16x32_bf16(aph, bvl, c, 0, 0, 0);
            c = __builtin_amdgcn_mfma_f32_16x16x32_bf16(apl, bvh, c, 0, 0, 0);
            o_[j] = c;
        }
    }

    // ---- epilogue: normalize and store ----
    #pragma unroll
    for (int r = 0; r < 4; ++r) {
        const int h = wsx * 16 + (lane >> 4) * 4 + r;
        #pragma unroll
        for (int j = 0; j < 4; ++j)
            wv[base + (size_t)h * 64 + j * 16 + (lane & 15)] = o_[j][r] * invs[r];
    }
}

// ---------------------------------------------------------------------------
// fused tail: out = relu(W2 * relu(W1 * wv + b1) + b2), per 64-col s-tile.
// Phase A: GEMM1 (persistent W1 frags, x staged like conv).
// Phase B: relu+bias -> split-bf16 'a' into LDS [64 s][256 k] (reuses x LDS).
// Phase C: GEMM2 streaming W2 frags from L2, B-frags from a-LDS.
// ---------------------------------------------------------------------------
__global__ __launch_bounds__(512, 2) void tail_fused_kernel(
    const float* __restrict__ x,
    const short* __restrict__ w1hi, const short* __restrict__ w1lo,
    const float* __restrict__ b1,
    const short* __restrict__ w2hi, const short* __restrict__ w2lo,
    const float* __restrict__ b2,
    float* __restrict__ out)
{
    __shared__ char lds[65536];   // phase A: xbuf[2] (hi+lo, 16 KB/buf) in first 32 KB
                                  // phase B/C: a_hi = lds[0..32K), a_lo = lds[32K..64K)
    const int tid  = threadIdx.x;
    const int lane = tid & 63;
    const int wave = tid >> 6;
    const size_t boff = (size_t)blockIdx.y * ((size_t)CC * DHWC);
    const int sT = blockIdx.x * 64;
    const float* xb = x + boff + sT;

    // persistent W1 A-frags
    bf16x8 ahi[2][8], alo[2][8];
    {
        const bf16x8* whf = (const bf16x8*)w1hi;
        const bf16x8* wlf = (const bf16x8*)w1lo;
        #pragma unroll
        for (int f = 0; f < 2; ++f) {
            const int fo = wave * 2 + f;
            #pragma unroll
            for (int t = 0; t < 8; ++t) {
                ahi[f][t] = whf[(fo * 8 + t) * 64 + lane];
                alo[f][t] = wlf[(fo * 8 + t) * 64 + lane];
            }
        }
    }

    f32x4 acc[2][4];
    #pragma unroll
    for (int f = 0; f < 2; ++f)
        #pragma unroll
        for (int j = 0; j < 4; ++j)
            acc[f][j] = (f32x4){0.f, 0.f, 0.f, 0.f};

    const int s_l = tid & 63;
    const int k8  = tid >> 6;

    float xr[8];
    #pragma unroll
    for (int r = 0; r < 8; ++r)
        xr[r] = xb[(size_t)(k8 * 8 + r) * DHWC + s_l];
    {
        bf16x8 hv, lv;
        #pragma unroll
        for (int r = 0; r < 8; ++r) {
            const short h = f2bf(xr[r]);
            hv[r] = h;
            lv[r] = f2bf(xr[r] - bf2f(h));
        }
        *(bf16x8*)(lds + swz(s_l, k8 * 8)) = hv;
        *(bf16x8*)(lds + 8192 + swz(s_l, k8 * 8)) = lv;
    }

    #pragma unroll
    for (int t = 0; t < 4; ++t) {
        if (t < 3) {
            #pragma unroll
            for (int r = 0; r < 8; ++r)
                xr[r] = xb[(size_t)((t + 1) * 64 + k8 * 8 + r) * DHWC + s_l];
        }
        __syncthreads();

        const char* bhib = lds + (t & 1) * 16384;
        const char* blob = bhib + 8192;
        #pragma unroll
        for (int kk = 0; kk < 2; ++kk) {
            bf16x8 bh[4], bl[4];
            #pragma unroll
            for (int j = 0; j < 4; ++j) {
                const int s = j * 16 + (lane & 15);
                const int k = kk * 32 + (lane >> 4) * 8;
                bh[j] = *(const bf16x8*)(bhib + swz(s, k));
                bl[j] = *(const bf16x8*)(blob + swz(s, k));
            }
            #pragma unroll
            for (int f = 0; f < 2; ++f)
                #pragma unroll
                for (int j = 0; j < 4; ++j) {
                    f32x4 c = acc[f][j];
                    c = __builtin_amdgcn_mfma_f32_16x16x32_bf16(ahi[f][2 * t + kk], bh[j], c, 0, 0, 0);
                    c = __builtin_amdgcn_mfma_f32_16x16x32_bf16(ahi[f][2 * t + kk], bl[j], c, 0, 0, 0);
                    c = __builtin_amdgcn_mfma_f32_16x16x32_bf16(alo[f][2 * t + kk], bh[j], c, 0, 0, 0);
                    acc[f][j] = c;
                }
        }

        if (t < 3) {
            bf16x8 hv, lv;
            #pragma unroll
            for (int r = 0; r < 8; ++r) {
                const short h = f2bf(xr[r]);
                hv[r] = h;
                lv[r] = f2bf(xr[r] - bf2f(h));
            }
            *(bf16x8*)(lds + ((t + 1) & 1) * 16384 + swz(s_l, k8 * 8)) = hv;
            *(bf16x8*)(lds + ((t + 1) & 1) * 16384 + 8192 + swz(s_l, k8 * 8)) = lv;
        }
    }

    // ---- phase B: a = relu(acc + b1) -> split bf16 into LDS [s][256] ----
    __syncthreads();   // all xbuf reads done; safe to overwrite lds[0..32K)
    #pragma unroll
    for (int f = 0; f < 2; ++f) {
        #pragma unroll
        for (int r = 0; r < 4; ++r) {
            const int o = wave * 32 + f * 16 + (lane >> 4) * 4 + r;
            const float bv = b1[o];
            #pragma unroll
            for (int j = 0; j < 4; ++j) {
                const int s = j * 16 + (lane & 15);
                const float val = fmaxf(acc[f][j][r] + bv, 0.f);
                const short h = f2bf(val);
                const int off = swz512(s, o);
                *(short*)(lds + off) = h;
                *(short*)(lds + 32768 + off) = f2bf(val - bf2f(h));
            }
        }
    }
    __syncthreads();

    // ---- phase C: GEMM2, W2 streamed from L2 ----
    f32x4 acc2[2][4];
    #pragma unroll
    for (int f = 0; f < 2; ++f)
        #pragma unroll
        for (int j = 0; j < 4; ++j)
            acc2[f][j] = (f32x4){0.f, 0.f, 0.f, 0.f};

    const bf16x8* w2hf = (const bf16x8*)w2hi;
    const bf16x8* w2lf = (const bf16x8*)w2lo;
    #pragma unroll
    for (int t2 = 0; t2 < 8; ++t2) {
        bf16x8 a2h[2], a2l[2];
        #pragma unroll
        for (int f = 0; f < 2; ++f) {
            const int idx = ((wave * 2 + f) * 8 + t2) * 64 + lane;
            a2h[f] = w2hf[idx];
            a2l[f] = w2lf[idx];
        }
        bf16x8 bh[4], bl[4];
        #pragma unroll
        for (int j = 0; j < 4; ++j) {
            const int s = j * 16 + (lane & 15);
            const int k = t2 * 32 + (lane >> 4) * 8;
            const int off = swz512(s, k);
            bh[j] = *(const bf16x8*)(lds + off);
            bl[j] = *(const bf16x8*)(lds + 32768 + off);
        }
        #pragma unroll
        for (int f = 0; f < 2; ++f)
            #pragma unroll
            for (int j = 0; j < 4; ++j) {
                f32x4 c = acc2[f][j];
                c = __builtin_amdgcn_mfma_f32_16x16x32_bf16(a2h[f], bh[j], c, 0, 0, 0);
                c = __builtin_amdgcn_mfma_f32_16x16x32_bf16(a2h[f], bl[j], c, 0, 0, 0);
                c = __builtin_amdgcn_mfma_f32_16x16x32_bf16(a2l[f], bh[j], c, 0, 0, 0);
                acc2[f][j] = c;
            }
    }

    // ---- epilogue 2 ----
    float* ob = out + boff + sT;
    const int n_l = lane & 15;
    const int m4  = (lane >> 4) * 4;
    #pragma unroll
    for (int f = 0; f < 2; ++f) {
        #pragma unroll
        for (int r = 0; r < 4; ++r) {
            const int o = wave * 32 + f * 16 + m4 + r;
            const float bv = b2[o];
            #pragma unroll
            for (int j = 0; j < 4; ++j) {
                const float val = fmaxf(acc2[f][j][r] + bv, 0.f);
                ob[(size_t)o * DHWC + j * 16 + n_l] = val;
            }
        }
    }
}

// ---------------------------------------------------------------------------
// Pipeline: prep W -> q=conv(eeg), k=conv(img), v=conv(img) -> attn(mfma) ->
//           out = tail_fused(wv).
// ws: qbuf (N f32) | kbuf (N f32) | wsplit (5 x 2 x 65536 bf16)
// ---------------------------------------------------------------------------
extern "C" void kernel_launch(void* const* d_in, const int* in_sizes, int n_in,
                              void* d_out, int out_size, void* d_ws, size_t ws_size,
                              hipStream_t stream)
{
    const float* eeg    = (const float*)d_in[0];
    const float* img    = (const float*)d_in[1];
    const float* q_w    = (const float*)d_in[2];
    const float* q_b    = (const float*)d_in[3];
    const float* k_w    = (const float*)d_in[4];
    const float* k_b    = (const float*)d_in[5];
    const float* v_w    = (const float*)d_in[6];
    const float* v_b    = (const float*)d_in[7];
    const float* attn_w = (const float*)d_in[8];
    const float* attn_b = (const float*)d_in[9];
    const float* out_w  = (const float*)d_in[10];
    const float* out_b  = (const float*)d_in[11];

    float* outp = (float*)d_out;
    const size_t N = (size_t)NBC * CC * DHWC;
    float* qbuf = (float*)d_ws;
    float* kbuf = qbuf + N;
    short* wsp  = (short*)(kbuf + N);

    hipLaunchKernelGGL(prep_w_kernel, dim3(16, 8, 5), dim3(64), 0, stream,
                       q_w, k_w, v_w, attn_w, out_w, wsp);

    const dim3 cgrid(DHWC / 64, NBC);
    const dim3 cblk(512);
    #define WMAT(m) (wsp + (size_t)(m) * 2 * 65536), (wsp + (size_t)(m) * 2 * 65536 + 65536)

    hipLaunchKernelGGL(conv_mfma_kernel, cgrid, cblk, 0, stream, eeg,  WMAT(0), q_b, qbuf, 0);
    hipLaunchKernelGGL(conv_mfma_kernel, cgrid, cblk, 0, stream, img,  WMAT(1), k_b, kbuf, 0);
    hipLaunchKernelGGL(conv_mfma_kernel, cgrid, cblk, 0, stream, img,  WMAT(2), v_b, outp, 0);
    hipLaunchKernelGGL(attn_mfma_kernel, dim3(NBC * CC * 16), dim3(256), 0, stream,
                       qbuf, kbuf, outp, qbuf);
    hipLaunchKernelGGL(tail_fused_kernel, cgrid, cblk, 0, stream,
                       qbuf, WMAT(3), attn_b, WMAT(4), out_b, outp);
    #undef WMAT
}

// Round 4
// 438.826 us; speedup vs baseline: 2.6333x; 1.1100x over previous
//
#include <hip/hip_runtime.h>

#define CC   256
#define DHWC 65536          // D*H*W
#define NBC  2              // batch

typedef __attribute__((ext_vector_type(8))) short bf16x8;
typedef __attribute__((ext_vector_type(4))) short bf16x4;
typedef __attribute__((ext_vector_type(4))) float f32x4;

// ---- bf16 split helpers (branchless, bit-level, RTN-even) --------------------
__device__ __forceinline__ short f2bf(float x) {
    unsigned u = __builtin_bit_cast(unsigned, x);
    unsigned r = (u + 0x7fffu + ((u >> 16) & 1u)) >> 16;
    return (short)r;
}
__device__ __forceinline__ float bf2f(short h) {
    unsigned u = ((unsigned)(unsigned short)h) << 16;
    return __builtin_bit_cast(float, u);
}

// swizzled byte offset into a [64 r][64 c] bf16 LDS plane (row stride 128 B).
__device__ __forceinline__ int swz(int r, int c) {
    return (r * 128 + c * 2) ^ ((r & 7) << 4);
}
// swizzled byte offset into a [64 s][256 k] bf16 LDS plane (row stride 512 B).
__device__ __forceinline__ int swz512(int s, int k) {
    return (s * 512 + k * 2) ^ ((s & 7) << 4);
}

// ---------------------------------------------------------------------------
// prep: split 5 weight matrices [256][256] fp32 into hi/lo bf16 planes stored
// fragment-major for mfma_f32_16x16x32_bf16 A-operand:
//   frag (fo = o/16, t = k/32): lane l holds W[fo*16 + (l&15)][t*32 + (l>>4)*8 + r]
// ---------------------------------------------------------------------------
__global__ void prep_w_kernel(const float* __restrict__ q_w, const float* __restrict__ k_w,
                              const float* __restrict__ v_w, const float* __restrict__ attn_w,
                              const float* __restrict__ out_w, short* __restrict__ wsp)
{
    const int l  = threadIdx.x;          // 64
    const int fo = blockIdx.x;           // 16
    const int t  = blockIdx.y;           // 8
    const int m  = blockIdx.z;           // 5
    const float* w = (m == 0) ? q_w : (m == 1) ? k_w : (m == 2) ? v_w
                   : (m == 3) ? attn_w : out_w;
    short* whi = wsp + (size_t)m * 2 * 65536;
    short* wlo = whi + 65536;

    const int o = fo * 16 + (l & 15);
    const int k = t * 32 + (l >> 4) * 8;

    bf16x8 hv, lv;
    #pragma unroll
    for (int r = 0; r < 8; ++r) {
        const float x = w[o * 256 + k + r];
        const short h = f2bf(x);
        hv[r] = h;
        lv[r] = f2bf(x - bf2f(h));
    }
    const int idx = (fo * 8 + t) * 64 + l;
    *(bf16x8*)(whi + idx * 8) = hv;
    *(bf16x8*)(wlo + idx * 8) = lv;
}

// ---------------------------------------------------------------------------
// conv1x1 via split-bf16 MFMA. W fragments STREAMED from L2 per K-step
// (frees 128 VGPRs -> 4 waves/SIMD under __launch_bounds__(512,4)).
// ---------------------------------------------------------------------------
__global__ __launch_bounds__(512, 4) void conv_mfma_kernel(
    const float* __restrict__ x, const short* __restrict__ whi,
    const short* __restrict__ wlo, const float* __restrict__ bias,
    float* __restrict__ out, const int do_relu)
{
    __shared__ bf16x8 xhi[2][512];   // [buf][64 s][64 k] bf16, 8 KB each
    __shared__ bf16x8 xlo[2][512];

    const int tid  = threadIdx.x;
    const int lane = tid & 63;
    const int wave = tid >> 6;            // 0..7
    const size_t boff = (size_t)blockIdx.y * ((size_t)CC * DHWC);
    const int sT = blockIdx.x * 64;
    const float* xb = x + boff + sT;
    const bf16x8* whf = (const bf16x8*)whi;
    const bf16x8* wlf = (const bf16x8*)wlo;

    f32x4 acc[2][4];
    #pragma unroll
    for (int f = 0; f < 2; ++f)
        #pragma unroll
        for (int j = 0; j < 4; ++j)
            acc[f][j] = (f32x4){0.f, 0.f, 0.f, 0.f};

    const int s_l = tid & 63;
    const int k8  = tid >> 6;

    float xr[8];
    #pragma unroll
    for (int r = 0; r < 8; ++r)
        xr[r] = xb[(size_t)(k8 * 8 + r) * DHWC + s_l];
    {
        bf16x8 hv, lv;
        #pragma unroll
        for (int r = 0; r < 8; ++r) {
            const short h = f2bf(xr[r]);
            hv[r] = h;
            lv[r] = f2bf(xr[r] - bf2f(h));
        }
        *(bf16x8*)((char*)xhi[0] + swz(s_l, k8 * 8)) = hv;
        *(bf16x8*)((char*)xlo[0] + swz(s_l, k8 * 8)) = lv;
    }

    #pragma unroll
    for (int t = 0; t < 4; ++t) {
        if (t < 3) {
            #pragma unroll
            for (int r = 0; r < 8; ++r)
                xr[r] = xb[(size_t)((t + 1) * 64 + k8 * 8 + r) * DHWC + s_l];
        }
        __syncthreads();

        const char* bhib = (const char*)xhi[t & 1];
        const char* blob = (const char*)xlo[t & 1];
        #pragma unroll
        for (int kk = 0; kk < 2; ++kk) {
            // stream this K-chunk's A fragments (L1/L2 resident)
            bf16x8 a1h[2], a1l[2];
            #pragma unroll
            for (int f = 0; f < 2; ++f) {
                const int idx = ((wave * 2 + f) * 8 + 2 * t + kk) * 64 + lane;
                a1h[f] = whf[idx];
                a1l[f] = wlf[idx];
            }
            bf16x8 bh[4], bl[4];
            #pragma unroll
            for (int j = 0; j < 4; ++j) {
                const int s = j * 16 + (lane & 15);
                const int k = kk * 32 + (lane >> 4) * 8;
                bh[j] = *(const bf16x8*)(bhib + swz(s, k));
                bl[j] = *(const bf16x8*)(blob + swz(s, k));
            }
            #pragma unroll
            for (int f = 0; f < 2; ++f)
                #pragma unroll
                for (int j = 0; j < 4; ++j) {
                    f32x4 c = acc[f][j];
                    c = __builtin_amdgcn_mfma_f32_16x16x32_bf16(a1h[f], bh[j], c, 0, 0, 0);
                    c = __builtin_amdgcn_mfma_f32_16x16x32_bf16(a1h[f], bl[j], c, 0, 0, 0);
                    c = __builtin_amdgcn_mfma_f32_16x16x32_bf16(a1l[f], bh[j], c, 0, 0, 0);
                    acc[f][j] = c;
                }
        }

        if (t < 3) {
            bf16x8 hv, lv;
            #pragma unroll
            for (int r = 0; r < 8; ++r) {
                const short h = f2bf(xr[r]);
                hv[r] = h;
                lv[r] = f2bf(xr[r] - bf2f(h));
            }
            *(bf16x8*)((char*)xhi[(t + 1) & 1] + swz(s_l, k8 * 8)) = hv;
            *(bf16x8*)((char*)xlo[(t + 1) & 1] + swz(s_l, k8 * 8)) = lv;
        }
    }

    float* ob = out + boff + sT;
    const int n_l = lane & 15;
    const int m4  = (lane >> 4) * 4;
    #pragma unroll
    for (int f = 0; f < 2; ++f) {
        #pragma unroll
        for (int r = 0; r < 4; ++r) {
            const int o = wave * 32 + f * 16 + m4 + r;
            const float bv = bias[o];
            #pragma unroll
            for (int j = 0; j < 4; ++j) {
                float val = acc[f][j][r] + bv;
                if (do_relu) val = fmaxf(val, 0.f);
                ob[(size_t)o * DHWC + j * 16 + n_l] = val;
            }
        }
    }
}

// ---------------------------------------------------------------------------
// attention via split-bf16 MFMA. One block (256 thr = 4 waves) per (b,c,d)
// slab. QK^T full split (3 MFMA). P and V single-bf16 (PV = 1 MFMA).
// LDS 5 planes x 8 KB = 40 KB -> 4 blocks/CU.
// ---------------------------------------------------------------------------
__global__ __launch_bounds__(256, 4) void attn_mfma_kernel(
    const float* __restrict__ q, const float* __restrict__ kg,
    const float* __restrict__ v, float* __restrict__ wv)
{
    __shared__ char lds[40960];
    const int QHI = 0, QLO = 8192, KHI = 16384, KLO = 24576, VTHI = 32768;

    const int tid  = threadIdx.x;
    const int lane = tid & 63;
    const int wsx  = tid >> 6;           // wave 0..3
    const size_t base = (size_t)blockIdx.x * 4096;

    // ---- stage q, k row-major split-bf16 ----
    {
        const int r  = tid >> 2;         // 0..63
        const int cb = (tid & 3) * 16;
        #pragma unroll
        for (int half = 0; half < 2; ++half) {
            const int c = cb + half * 8;
            const float4 qa = *(const float4*)(q  + base + r * 64 + c);
            const float4 qb = *(const float4*)(q  + base + r * 64 + c + 4);
            const float4 ka = *(const float4*)(kg + base + r * 64 + c);
            const float4 kb = *(const float4*)(kg + base + r * 64 + c + 4);
            bf16x8 qh, ql, kh, kl;
            #pragma unroll
            for (int e = 0; e < 4; ++e) {
                float xq = ((const float*)&qa)[e];
                short h = f2bf(xq); qh[e] = h; ql[e] = f2bf(xq - bf2f(h));
                xq = ((const float*)&qb)[e];
                h = f2bf(xq); qh[e + 4] = h; ql[e + 4] = f2bf(xq - bf2f(h));
                float xk = ((const float*)&ka)[e];
                h = f2bf(xk); kh[e] = h; kl[e] = f2bf(xk - bf2f(h));
                xk = ((const float*)&kb)[e];
                h = f2bf(xk); kh[e + 4] = h; kl[e + 4] = f2bf(xk - bf2f(h));
            }
            const int off = swz(r, c);
            *(bf16x8*)(lds + QHI + off) = qh;
            *(bf16x8*)(lds + QLO + off) = ql;
            *(bf16x8*)(lds + KHI + off) = kh;
            *(bf16x8*)(lds + KLO + off) = kl;
        }
        // ---- stage V transposed (hi only): vt[w][x] = V[x][w] ----
        const int x0 = (tid >> 4) * 4;   // 0..60
        const int w0 = (tid & 15) * 4;   // 0..60
        float4 vr[4];
        #pragma unroll
        for (int i = 0; i < 4; ++i)
            vr[i] = *(const float4*)(v + base + (size_t)(x0 + i) * 64 + w0);
        #pragma unroll
        for (int j = 0; j < 4; ++j) {
            bf16x4 h4;
            #pragma unroll
            for (int i = 0; i < 4; ++i)
                h4[i] = f2bf(((const float*)&vr[i])[j]);
            *(bf16x4*)(lds + VTHI + swz(w0 + j, x0)) = h4;
        }
    }
    __syncthreads();

    // ---- QK^T: S[h][x] for h in own strip (full split, 3 MFMA) ----
    f32x4 acc[4];
    #pragma unroll
    for (int j = 0; j < 4; ++j) acc[j] = (f32x4){0.f, 0.f, 0.f, 0.f};

    const int arow = wsx * 16 + (lane & 15);
    #pragma unroll
    for (int kk = 0; kk < 2; ++kk) {
        const int kcol = kk * 32 + (lane >> 4) * 8;
        const bf16x8 aqh = *(const bf16x8*)(lds + QHI + swz(arow, kcol));
        const bf16x8 aql = *(const bf16x8*)(lds + QLO + swz(arow, kcol));
        #pragma unroll
        for (int j = 0; j < 4; ++j) {
            const int brow = j * 16 + (lane & 15);
            const bf16x8 bkh = *(const bf16x8*)(lds + KHI + swz(brow, kcol));
            const bf16x8 bkl = *(const bf16x8*)(lds + KLO + swz(brow, kcol));
            f32x4 c = acc[j];
            c = __builtin_amdgcn_mfma_f32_16x16x32_bf16(aqh, bkh, c, 0, 0, 0);
            c = __builtin_amdgcn_mfma_f32_16x16x32_bf16(aqh, bkl, c, 0, 0, 0);
            c = __builtin_amdgcn_mfma_f32_16x16x32_bf16(aql, bkh, c, 0, 0, 0);
            acc[j] = c;
        }
    }

    // ---- softmax over x. Row r of lane: h = 16ws + (l>>4)*4 + r. ----
    float p[4][4], invs[4];
    #pragma unroll
    for (int r = 0; r < 4; ++r) {
        float m = fmaxf(fmaxf(acc[0][r], acc[1][r]), fmaxf(acc[2][r], acc[3][r]));
        m = fmaxf(m, __shfl_xor(m, 1));
        m = fmaxf(m, __shfl_xor(m, 2));
        m = fmaxf(m, __shfl_xor(m, 4));
        m = fmaxf(m, __shfl_xor(m, 8));
        float s = 0.f;
        #pragma unroll
        for (int j = 0; j < 4; ++j) { p[j][r] = __expf(acc[j][r] - m); s += p[j][r]; }
        s += __shfl_xor(s, 1);
        s += __shfl_xor(s, 2);
        s += __shfl_xor(s, 4);
        s += __shfl_xor(s, 8);
        invs[r] = 1.f / s;
    }

    __syncthreads();   // QK reads of q planes done -> safe to overwrite with P

    // ---- write unnormalized P (hi only) into QHI plane, own strip rows ----
    #pragma unroll
    for (int r = 0; r < 4; ++r) {
        const int row = wsx * 16 + (lane >> 4) * 4 + r;
        #pragma unroll
        for (int j = 0; j < 4; ++j) {
            const int col = j * 16 + (lane & 15);
            *(short*)(lds + QHI + swz(row, col)) = f2bf(p[j][r]);
        }
    }
    __syncthreads();

    // ---- PV: wv[h][w] = sum_x P[h][x] V[x][w]  (1 MFMA per frag) ----
    f32x4 o_[4];
    #pragma unroll
    for (int j = 0; j < 4; ++j) o_[j] = (f32x4){0.f, 0.f, 0.f, 0.f};

    #pragma unroll
    for (int kk = 0; kk < 2; ++kk) {
        const int kcol = kk * 32 + (lane >> 4) * 8;
        const bf16x8 aph = *(const bf16x8*)(lds + QHI + swz(arow, kcol));
        #pragma unroll
        for (int j = 0; j < 4; ++j) {
            const int brow = j * 16 + (lane & 15);
            const bf16x8 bvh = *(const bf16x8*)(lds + VTHI + swz(brow, kcol));
            o_[j] = __builtin_amdgcn_mfma_f32_16x16x32_bf16(aph, bvh, o_[j], 0, 0, 0);
        }
    }

    // ---- epilogue: normalize and store ----
    #pragma unroll
    for (int r = 0; r < 4; ++r) {
        const int h = wsx * 16 + (lane >> 4) * 4 + r;
        #pragma unroll
        for (int j = 0; j < 4; ++j)
            wv[base + (size_t)h * 64 + j * 16 + (lane & 15)] = o_[j][r] * invs[r];
    }
}

// ---------------------------------------------------------------------------
// fused tail: out = relu(W2 * relu(W1 * wv + b1) + b2), per 64-col s-tile.
// W1 and W2 fragments streamed from L2; __launch_bounds__(512,4).
// ---------------------------------------------------------------------------
__global__ __launch_bounds__(512, 4) void tail_fused_kernel(
    const float* __restrict__ x,
    const short* __restrict__ w1hi, const short* __restrict__ w1lo,
    const float* __restrict__ b1,
    const short* __restrict__ w2hi, const short* __restrict__ w2lo,
    const float* __restrict__ b2,
    float* __restrict__ out)
{
    __shared__ char lds[65536];   // phase A: xbuf[2] (hi+lo, 16 KB/buf) in first 32 KB
                                  // phase B/C: a_hi = lds[0..32K), a_lo = lds[32K..64K)
    const int tid  = threadIdx.x;
    const int lane = tid & 63;
    const int wave = tid >> 6;
    const size_t boff = (size_t)blockIdx.y * ((size_t)CC * DHWC);
    const int sT = blockIdx.x * 64;
    const float* xb = x + boff + sT;
    const bf16x8* w1hf = (const bf16x8*)w1hi;
    const bf16x8* w1lf = (const bf16x8*)w1lo;

    f32x4 acc[2][4];
    #pragma unroll
    for (int f = 0; f < 2; ++f)
        #pragma unroll
        for (int j = 0; j < 4; ++j)
            acc[f][j] = (f32x4){0.f, 0.f, 0.f, 0.f};

    const int s_l = tid & 63;
    const int k8  = tid >> 6;

    float xr[8];
    #pragma unroll
    for (int r = 0; r < 8; ++r)
        xr[r] = xb[(size_t)(k8 * 8 + r) * DHWC + s_l];
    {
        bf16x8 hv, lv;
        #pragma unroll
        for (int r = 0; r < 8; ++r) {
            const short h = f2bf(xr[r]);
            hv[r] = h;
            lv[r] = f2bf(xr[r] - bf2f(h));
        }
        *(bf16x8*)(lds + swz(s_l, k8 * 8)) = hv;
        *(bf16x8*)(lds + 8192 + swz(s_l, k8 * 8)) = lv;
    }

    #pragma unroll
    for (int t = 0; t < 4; ++t) {
        if (t < 3) {
            #pragma unroll
            for (int r = 0; r < 8; ++r)
                xr[r] = xb[(size_t)((t + 1) * 64 + k8 * 8 + r) * DHWC + s_l];
        }
        __syncthreads();

        const char* bhib = lds + (t & 1) * 16384;
        const char* blob = bhib + 8192;
        #pragma unroll
        for (int kk = 0; kk < 2; ++kk) {
            bf16x8 a1h[2], a1l[2];
            #pragma unroll
            for (int f = 0; f < 2; ++f) {
                const int idx = ((wave * 2 + f) * 8 + 2 * t + kk) * 64 + lane;
                a1h[f] = w1hf[idx];
                a1l[f] = w1lf[idx];
            }
            bf16x8 bh[4], bl[4];
            #pragma unroll
            for (int j = 0; j < 4; ++j) {
                const int s = j * 16 + (lane & 15);
                const int k = kk * 32 + (lane >> 4) * 8;
                bh[j] = *(const bf16x8*)(bhib + swz(s, k));
                bl[j] = *(const bf16x8*)(blob + swz(s, k));
            }
            #pragma unroll
            for (int f = 0; f < 2; ++f)
                #pragma unroll
                for (int j = 0; j < 4; ++j) {
                    f32x4 c = acc[f][j];
                    c = __builtin_amdgcn_mfma_f32_16x16x32_bf16(a1h[f], bh[j], c, 0, 0, 0);
                    c = __builtin_amdgcn_mfma_f32_16x16x32_bf16(a1h[f], bl[j], c, 0, 0, 0);
                    c = __builtin_amdgcn_mfma_f32_16x16x32_bf16(a1l[f], bh[j], c, 0, 0, 0);
                    acc[f][j] = c;
                }
        }

        if (t < 3) {
            bf16x8 hv, lv;
            #pragma unroll
            for (int r = 0; r < 8; ++r) {
                const short h = f2bf(xr[r]);
                hv[r] = h;
                lv[r] = f2bf(xr[r] - bf2f(h));
            }
            *(bf16x8*)(lds + ((t + 1) & 1) * 16384 + swz(s_l, k8 * 8)) = hv;
            *(bf16x8*)(lds + ((t + 1) & 1) * 16384 + 8192 + swz(s_l, k8 * 8)) = lv;
        }
    }

    // ---- phase B: a = relu(acc + b1) -> split bf16 into LDS [s][256] ----
    __syncthreads();   // all xbuf reads done; safe to overwrite lds[0..32K)
    #pragma unroll
    for (int f = 0; f < 2; ++f) {
        #pragma unroll
        for (int r = 0; r < 4; ++r) {
            const int o = wave * 32 + f * 16 + (lane >> 4) * 4 + r;
            const float bv = b1[o];
            #pragma unroll
            for (int j = 0; j < 4; ++j) {
                const int s = j * 16 + (lane & 15);
                const float val = fmaxf(acc[f][j][r] + bv, 0.f);
                const short h = f2bf(val);
                const int off = swz512(s, o);
                *(short*)(lds + off) = h;
                *(short*)(lds + 32768 + off) = f2bf(val - bf2f(h));
            }
        }
    }
    __syncthreads();

    // ---- phase C: GEMM2, W2 streamed from L2 ----
    f32x4 acc2[2][4];
    #pragma unroll
    for (int f = 0; f < 2; ++f)
        #pragma unroll
        for (int j = 0; j < 4; ++j)
            acc2[f][j] = (f32x4){0.f, 0.f, 0.f, 0.f};

    const bf16x8* w2hf = (const bf16x8*)w2hi;
    const bf16x8* w2lf = (const bf16x8*)w2lo;
    #pragma unroll
    for (int t2 = 0; t2 < 8; ++t2) {
        bf16x8 a2h[2], a2l[2];
        #pragma unroll
        for (int f = 0; f < 2; ++f) {
            const int idx = ((wave * 2 + f) * 8 + t2) * 64 + lane;
            a2h[f] = w2hf[idx];
            a2l[f] = w2lf[idx];
        }
        bf16x8 bh[4], bl[4];
        #pragma unroll
        for (int j = 0; j < 4; ++j) {
            const int s = j * 16 + (lane & 15);
            const int k = t2 * 32 + (lane >> 4) * 8;
            const int off = swz512(s, k);
            bh[j] = *(const bf16x8*)(lds + off);
            bl[j] = *(const bf16x8*)(lds + 32768 + off);
        }
        #pragma unroll
        for (int f = 0; f < 2; ++f)
            #pragma unroll
            for (int j = 0; j < 4; ++j) {
                f32x4 c = acc2[f][j];
                c = __builtin_amdgcn_mfma_f32_16x16x32_bf16(a2h[f], bh[j], c, 0, 0, 0);
                c = __builtin_amdgcn_mfma_f32_16x16x32_bf16(a2h[f], bl[j], c, 0, 0, 0);
                c = __builtin_amdgcn_mfma_f32_16x16x32_bf16(a2l[f], bh[j], c, 0, 0, 0);
                acc2[f][j] = c;
            }
    }

    // ---- epilogue 2 ----
    float* ob = out + boff + sT;
    const int n_l = lane & 15;
    const int m4  = (lane >> 4) * 4;
    #pragma unroll
    for (int f = 0; f < 2; ++f) {
        #pragma unroll
        for (int r = 0; r < 4; ++r) {
            const int o = wave * 32 + f * 16 + m4 + r;
            const float bv = b2[o];
            #pragma unroll
            for (int j = 0; j < 4; ++j) {
                const float val = fmaxf(acc2[f][j][r] + bv, 0.f);
                ob[(size_t)o * DHWC + j * 16 + n_l] = val;
            }
        }
    }
}

// ---------------------------------------------------------------------------
// Pipeline: prep W -> q=conv(eeg), k=conv(img), v=conv(img) -> attn(mfma) ->
//           out = tail_fused(wv).
// ws: qbuf (N f32) | kbuf (N f32) | wsplit (5 x 2 x 65536 bf16)
// ---------------------------------------------------------------------------
extern "C" void kernel_launch(void* const* d_in, const int* in_sizes, int n_in,
                              void* d_out, int out_size, void* d_ws, size_t ws_size,
                              hipStream_t stream)
{
    const float* eeg    = (const float*)d_in[0];
    const float* img    = (const float*)d_in[1];
    const float* q_w    = (const float*)d_in[2];
    const float* q_b    = (const float*)d_in[3];
    const float* k_w    = (const float*)d_in[4];
    const float* k_b    = (const float*)d_in[5];
    const float* v_w    = (const float*)d_in[6];
    const float* v_b    = (const float*)d_in[7];
    const float* attn_w = (const float*)d_in[8];
    const float* attn_b = (const float*)d_in[9];
    const float* out_w  = (const float*)d_in[10];
    const float* out_b  = (const float*)d_in[11];

    float* outp = (float*)d_out;
    const size_t N = (size_t)NBC * CC * DHWC;
    float* qbuf = (float*)d_ws;
    float* kbuf = qbuf + N;
    short* wsp  = (short*)(kbuf + N);

    hipLaunchKernelGGL(prep_w_kernel, dim3(16, 8, 5), dim3(64), 0, stream,
                       q_w, k_w, v_w, attn_w, out_w, wsp);

    const dim3 cgrid(DHWC / 64, NBC);
    const dim3 cblk(512);
    #define WMAT(m) (wsp + (size_t)(m) * 2 * 65536), (wsp + (size_t)(m) * 2 * 65536 + 65536)

    hipLaunchKernelGGL(conv_mfma_kernel, cgrid, cblk, 0, stream, eeg,  WMAT(0), q_b, qbuf, 0);
    hipLaunchKernelGGL(conv_mfma_kernel, cgrid, cblk, 0, stream, img,  WMAT(1), k_b, kbuf, 0);
    hipLaunchKernelGGL(conv_mfma_kernel, cgrid, cblk, 0, stream, img,  WMAT(2), v_b, outp, 0);
    hipLaunchKernelGGL(attn_mfma_kernel, dim3(NBC * CC * 16), dim3(256), 0, stream,
                       qbuf, kbuf, outp, qbuf);
    hipLaunchKernelGGL(tail_fused_kernel, cgrid, cblk, 0, stream,
                       qbuf, WMAT(3), attn_b, WMAT(4), out_b, outp);
    #undef WMAT
}